// Round 7
// baseline (473.644 us; speedup 1.0000x reference)
//
#include <hip/hip_runtime.h>
#include <hip/hip_bf16.h>

namespace {

constexpr int D    = 512;
constexpr int S    = 1536;
constexpr int N    = S + 1;      // 1537
constexpr int L    = 4;
constexpr int H    = 4;
constexpr int R    = 32;
constexpr int W    = 128;
constexpr int HFF  = 1024;
constexpr float EPS = 1e-5f;

// attention: 4 tokens/block, shared neighbor span
constexpr int TB   = 4;
constexpr int NB4  = (N + TB - 1) / TB;   // 385 blocks
constexpr int SP   = 133;    // c=0..131 window span (g = n0-W+c), c=132 anchor
constexpr int SPAD = 136;    // padded row stride

typedef __attribute__((ext_vector_type(8))) short short8;
typedef __attribute__((ext_vector_type(4))) float floatx4;

__device__ inline ushort f2bf(float x){
  __hip_bfloat16 h = __float2bfloat16(x);
  return *reinterpret_cast<ushort*>(&h);
}
__device__ inline float bf2f(uint u){
  union { uint u; float f; } c; c.u = u << 16; return c.f;
}

// ---------------- reductions ------------------------------------------------
__device__ inline float wave_sum(float v){
#pragma unroll
  for (int o = 32; o; o >>= 1) v += __shfl_xor(v, o, 64);
  return v;
}
__device__ inline float wave_max(float v){
#pragma unroll
  for (int o = 32; o; o >>= 1) v = fmaxf(v, __shfl_xor(v, o, 64));
  return v;
}
__device__ inline float block_sum(float v, float* scr){
  v = wave_sum(v);
  __syncthreads();
  if ((threadIdx.x & 63) == 0) scr[threadIdx.x >> 6] = v;
  __syncthreads();
  return scr[0] + scr[1] + scr[2] + scr[3];
}

// ---------------- pack wq/wk -> bf16 [l][c][d], c = q(0..127)|k(128..255) ----
__global__ __launch_bounds__(256) void pack_wqk_bf(const float* __restrict__ wq,
                                                   const float* __restrict__ wk,
                                                   ushort* __restrict__ out){
  int i = blockIdx.x * 256 + threadIdx.x;   // L*256*512
  int d = i & 511;
  int c = (i >> 9) & 255;
  int l = i >> 17;
  int cc = c & 127;
  int h = cc >> 5, r = cc & 31;
  const float* src = (c < 128) ? wq : wk;
  out[i] = f2bf(src[((l * H + h) * D + d) * R + r]);
}

// ---------------- fp32 [rows][cols] -> bf16 [cols][rows], per-layer grid.z ---
__global__ __launch_bounds__(256) void transpose_bf(const float* __restrict__ src,
                                                    ushort* __restrict__ dst,
                                                    int rows, int cols){
  __shared__ float tile[32][33];
  const float* s = src + (size_t)blockIdx.z * rows * cols;
  ushort* d = dst + (size_t)blockIdx.z * rows * cols;
  int c0 = blockIdx.x * 32, r0 = blockIdx.y * 32;
  int tx = threadIdx.x & 31, ty = threadIdx.x >> 5;
  for (int rr = ty; rr < 32; rr += 8)
    tile[rr][tx] = s[(size_t)(r0 + rr) * cols + c0 + tx];
  __syncthreads();
  for (int rr = ty; rr < 32; rr += 8)
    d[(size_t)(c0 + rr) * rows + r0 + tx] = f2bf(tile[tx][rr]);
}

// ---------------- embedding + input LN + tok_state --------------------------
__global__ __launch_bounds__(256) void embed_ln_kernel(
    const int* __restrict__ ids, const float* __restrict__ embed,
    const float* __restrict__ pos, const float* __restrict__ g,
    const float* __restrict__ b, const float* __restrict__ anchor_val,
    const float* __restrict__ anchor_state, const float* __restrict__ state_w,
    const float* __restrict__ state_b, float* __restrict__ val,
    ushort* __restrict__ valbf, float* __restrict__ state)
{
  __shared__ float scr[4];
  int n = blockIdx.x, t = threadIdx.x;
  if (n == 0){
    float a0 = anchor_val[t], a1 = anchor_val[t + 256];
    val[t] = a0; val[t + 256] = a1;
    valbf[t] = f2bf(a0); valbf[t + 256] = f2bf(a1);
    if (t == 0) state[0] = anchor_state[0];
    return;
  }
  int tp = n - 1;
  int id = ids[tp];
  float x0 = embed[(size_t)id * D + t]       + pos[tp * D + t];
  float x1 = embed[(size_t)id * D + t + 256] + pos[tp * D + t + 256];
  float mean = block_sum(x0 + x1, scr) * (1.f / D);
  float var  = block_sum(x0 * x0 + x1 * x1, scr) * (1.f / D) - mean * mean;
  float rs   = rsqrtf(var + EPS);
  float y0 = (x0 - mean) * rs * g[t]       + b[t];
  float y1 = (x1 - mean) * rs * g[t + 256] + b[t + 256];
  val[n * D + t]       = y0;
  val[n * D + t + 256] = y1;
  valbf[n * D + t]       = f2bf(y0);
  valbf[n * D + t + 256] = f2bf(y1);
  float ts = block_sum(y0 * state_w[t] + y1 * state_w[t + 256], scr);
  if (t == 0) state[n] = ts + state_b[0];
}

// ---------------- bf16 MFMA GEMM, direct-from-global fragments ---------------
// A: [M][Kd] bf16; Bt: [Nc][Kd] bf16. 64x64 tile, 256 threads = 4 waves, each
// wave a 32x32 quadrant (2x2 MFMA 16x16x32). No LDS, no barriers: each lane
// loads its A/B fragments straight from global (16B, matches A-operand layout
// lane(q,lm) <- A[m=lm][k=q*8+j]). Waves are independent; unroll-8 keeps many
// loads in flight. OOB A rows clamp to M-1: a clamped lane only feeds output
// rows >= M, which the epilogue skips.
template<int ACT>
__global__ __launch_bounds__(256) void gemm_bf16(
    const ushort* __restrict__ A, const ushort* __restrict__ Bt,
    const float* __restrict__ bias, const float* __restrict__ resid,
    float* __restrict__ C, ushort* __restrict__ Cbf,
    int M, int Kd, int Nc)
{
  int row0 = blockIdx.y * 64;
  int col0 = blockIdx.x * 64;
  int t = threadIdx.x;
  int lane = t & 63, w = t >> 6;
  int wr = w >> 1, wc = w & 1;
  int q = lane >> 4, lm = lane & 15;

  const int ra = row0 + wr * 32 + lm;
  const int cb = col0 + wc * 32 + lm;
  const int ra0 = min(ra, M - 1);
  const int ra1 = min(ra + 16, M - 1);
  const ushort* pa0 = A  + (size_t)ra0 * Kd + q * 8;
  const ushort* pa1 = A  + (size_t)ra1 * Kd + q * 8;
  const ushort* pb0 = Bt + (size_t)cb * Kd + q * 8;
  const ushort* pb1 = Bt + (size_t)(cb + 16) * Kd + q * 8;

  floatx4 acc00 = {0.f,0.f,0.f,0.f}, acc01 = acc00, acc10 = acc00, acc11 = acc00;

#pragma unroll 8
  for (int k = 0; k < Kd; k += 32){
    short8 a0 = *(const short8*)(pa0 + k);
    short8 a1 = *(const short8*)(pa1 + k);
    short8 b0 = *(const short8*)(pb0 + k);
    short8 b1 = *(const short8*)(pb1 + k);
    acc00 = __builtin_amdgcn_mfma_f32_16x16x32_bf16(a0, b0, acc00, 0, 0, 0);
    acc01 = __builtin_amdgcn_mfma_f32_16x16x32_bf16(a0, b1, acc01, 0, 0, 0);
    acc10 = __builtin_amdgcn_mfma_f32_16x16x32_bf16(a1, b0, acc10, 0, 0, 0);
    acc11 = __builtin_amdgcn_mfma_f32_16x16x32_bf16(a1, b1, acc11, 0, 0, 0);
  }

  // epilogue: C/D layout col = lane&15, row = (lane>>4)*4 + reg  [m89]
#pragma unroll
  for (int i = 0; i < 2; ++i){
#pragma unroll
    for (int j = 0; j < 2; ++j){
      const floatx4& a4 = i == 0 ? (j == 0 ? acc00 : acc01)
                                 : (j == 0 ? acc10 : acc11);
      int col = col0 + wc * 32 + j * 16 + lm;
#pragma unroll
      for (int r = 0; r < 4; ++r){
        int row = row0 + wr * 32 + i * 16 + q * 4 + r;
        if (row >= M) continue;
        float v = a4[r] + (bias ? bias[col] : 0.f);
        if (ACT == 1) v = 0.5f * v * (1.f + erff(v * 0.70710678118654752f));
        if (resid) v += resid[(size_t)row * Nc + col];
        size_t o = (size_t)row * Nc + col;
        if (C)   C[o] = v;
        if (Cbf) Cbf[o] = f2bf(v);
      }
    }
  }
}

// ---------------- attention, 4 tokens per block ------------------------------
// qkbf: [N][256] bf16 (q 0..127 = h*32+r, k 128..255).
// Span col c: 0..131 -> global g = n0 - W + c (clamped); c=132 -> anchor (0).
// Token i (n = n0+i) window = c in [i, i+128]; anchor valid iff n > W.
__global__ __launch_bounds__(256) void attn4_kernel(
    const ushort* __restrict__ qkbf, const float* __restrict__ val0,
    const ushort* __restrict__ val0bf, const float* __restrict__ state_in,
    float* __restrict__ val1, ushort* __restrict__ x2bf,
    float* __restrict__ state_out,
    const float* __restrict__ gate_p, const float* __restrict__ lng,
    const float* __restrict__ lnb, const float* __restrict__ ln2g,
    const float* __restrict__ ln2b)
{
  __shared__ float kg[64 * SPAD];   // [ch_local][c], reused as xbuf[4][520] later
  __shared__ float qsh[TB * 128];
  __shared__ float ssh[16 * SPAD];  // [tok*4+h][c]
  __shared__ float ash[TB * SPAD];  // a then e, row per token
  const int n0 = blockIdx.x * TB;
  const int t = threadIdx.x;
  const int w = t >> 6, l = t & 63;   // wave = token index
  const float gate = gate_p[0];
  const float scale = 0.17677669529663687f;  // 1/sqrt(32)

  // ---- stage q (4 tokens x 128 ch)
#pragma unroll
  for (int i = t; i < TB * 128; i += 256){
    int it = i >> 7, ch = i & 127;
    int gr = min(n0 + it, N - 1);
    qsh[i] = bf2f((uint)qkbf[(size_t)gr * 256 + ch]);
  }

  // ---- scores, two halves of 64 channels
  for (int half = 0; half < 2; ++half){
    for (int i = t; i < SP * 16; i += 256){
      int c = i >> 4, c4 = i & 15;
      int g = (c == 132) ? 0 : min(max(n0 - W + c, 0), N - 1);
      uint2 v = *(const uint2*)&qkbf[(size_t)g * 256 + 128 + half * 64 + c4 * 4];
      int ch = c4 * 4;
      kg[(ch + 0) * SPAD + c] = bf2f(v.x & 0xffffu);
      kg[(ch + 1) * SPAD + c] = bf2f(v.x >> 16);
      kg[(ch + 2) * SPAD + c] = bf2f(v.y & 0xffffu);
      kg[(ch + 3) * SPAD + c] = bf2f(v.y >> 16);
    }
    __syncthreads();
    for (int tk = t; tk < TB * 2 * SP; tk += 256){
      int c = tk % SP;
      int th = tk / SP;            // 0..7
      int tok = th & 3, hh = th >> 2;
      int h = half * 2 + hh;
      const float* qs = &qsh[tok * 128 + h * 32];
      const float* ks = &kg[hh * 32 * SPAD + c];
      float acc = 0.f;
#pragma unroll
      for (int r = 0; r < 32; ++r) acc += qs[r] * ks[r * SPAD];
      ssh[(tok * 4 + h) * SPAD + c] = acc * scale;
    }
    __syncthreads();
  }

  // ---- per-(tok,c) head softmax -> a
  for (int i = t; i < TB * SP; i += 256){
    int tok = i / SP, c = i - tok * SP;
    const float* sr = &ssh[tok * 4 * SPAD + c];
    float s0 = sr[0], s1 = sr[SPAD], s2 = sr[2 * SPAD], s3 = sr[3 * SPAD];
    float a0 = fabsf(s0), a1 = fabsf(s1), a2 = fabsf(s2), a3 = fabsf(s3);
    float m = fmaxf(fmaxf(a0, a1), fmaxf(a2, a3));
    float w0 = expf(a0 - m), w1 = expf(a1 - m), w2 = expf(a2 - m), w3 = expf(a3 - m);
    ash[tok * SPAD + c] = (s0 * w0 + s1 * w1 + s2 * w2 + s3 * w3) / (w0 + w1 + w2 + w3);
  }
  __syncthreads();

  // ---- per-token signed softmax over span (wave w <-> token w), e in place
  {
    const int n = n0 + w;
    float* arow = &ash[w * SPAD];
    float a0 = arow[l];
    float a1 = arow[64 + l];
    float a2 = (l < 5) ? arow[128 + l] : 0.f;
    bool ok0 = (l >= w) && (n0 - W + l >= 0);
    bool ok1 = (n0 - W + 64 + l >= 0);
    bool ok2;
    if (l < 4)       ok2 = (l <= w);          // window col 128+l, g = n0+l >= 0
    else if (l == 4) ok2 = (n > W);           // anchor (c=132)
    else             ok2 = false;
    float cand = -3.4e38f;
    if (ok0) cand = fabsf(a0);
    if (ok1) cand = fmaxf(cand, fabsf(a1));
    if (ok2) cand = fmaxf(cand, fabsf(a2));
    float m = wave_max(cand);
    float e0 = ok0 ? expf(fabsf(a0) - m) : 0.f;
    float e1 = ok1 ? expf(fabsf(a1) - m) : 0.f;
    float e2 = ok2 ? expf(fabsf(a2) - m) : 0.f;
    float inv = 1.f / wave_sum(e0 + e1 + e2);
    int g0 = min(max(n0 - W + l, 0), N - 1);
    int g1 = min(max(n0 - W + 64 + l, 0), N - 1);
    int g2 = (l < 4) ? min(n0 + l, N - 1) : 0;
    float sg0 = (a0 > 0.f) ? 1.f : ((a0 < 0.f) ? -1.f : 0.f);
    float sg1 = (a1 > 0.f) ? 1.f : ((a1 < 0.f) ? -1.f : 0.f);
    float sg2 = (a2 > 0.f) ? 1.f : ((a2 < 0.f) ? -1.f : 0.f);
    float t0 = sg0 * e0 * inv * state_in[g0];
    float t1 = sg1 * e1 * inv * state_in[g1];
    float t2 = (l < 5) ? sg2 * e2 * inv * state_in[g2] : 0.f;
    arow[l] = t0;
    arow[64 + l] = t1;
    if (l < 5) arow[128 + l] = t2;
    float ds = wave_sum(t0 + t1 + t2);
    if (l == 0 && n < N) state_out[n] = state_in[n] + gate * ds;
  }
  __syncthreads();

  // ---- d_val: stream span rows once (bf16), 4 accumulators per thread
  float acc[TB][2];
#pragma unroll
  for (int k = 0; k < TB; ++k){ acc[k][0] = 0.f; acc[k][1] = 0.f; }
  {
    const int d0 = 2 * t;
    for (int c = 0; c < SP; ++c){
      int g = (c == 132) ? 0 : min(max(n0 - W + c, 0), N - 1);
      uint v = *(const uint*)&val0bf[(size_t)g * D + d0];
      float vx = bf2f(v & 0xffffu), vy = bf2f(v >> 16);
#pragma unroll
      for (int k = 0; k < TB; ++k){
        float e = ash[k * SPAD + c];
        acc[k][0] += e * vx;
        acc[k][1] += e * vy;
      }
    }
  }
  // residual into xbuf (reuse kg; kg dead after scores)
  float* xbuf = kg;    // [4][520]
  {
    const int d0 = 2 * t;
#pragma unroll
    for (int k = 0; k < TB; ++k){
      int nc = min(n0 + k, N - 1);
      float2 vv = *(const float2*)&val0[(size_t)nc * D + d0];
      xbuf[k * 520 + d0]     = vv.x + gate * acc[k][0];
      xbuf[k * 520 + d0 + 1] = vv.y + gate * acc[k][1];
    }
  }
  __syncthreads();

  // ---- LN1 -> val1, LN2 -> x2bf (wave per token, 8 dims per lane)
  {
    const int n = n0 + w;
    const int d = l * 8;
    const float* xr = &xbuf[w * 520 + d];
    float x[8];
#pragma unroll
    for (int j = 0; j < 8; ++j) x[j] = xr[j];
    float s1 = 0.f, s2 = 0.f;
#pragma unroll
    for (int j = 0; j < 8; ++j){ s1 += x[j]; s2 += x[j] * x[j]; }
    s1 = wave_sum(s1); s2 = wave_sum(s2);
    float mean = s1 * (1.f / D);
    float var  = s2 * (1.f / D) - mean * mean;
    float rs   = rsqrtf(var + EPS);
    float y[8];
    float u1 = 0.f, u2 = 0.f;
#pragma unroll
    for (int j = 0; j < 8; ++j){
      float yv = (x[j] - mean) * rs * lng[d + j] + lnb[d + j];
      y[j] = yv; u1 += yv; u2 += yv * yv;
    }
    u1 = wave_sum(u1); u2 = wave_sum(u2);
    float mean2 = u1 * (1.f / D);
    float var2  = u2 * (1.f / D) - mean2 * mean2;
    float rs2   = rsqrtf(var2 + EPS);
    if (n < N){
      *(float4*)&val1[(size_t)n * D + d]     = make_float4(y[0], y[1], y[2], y[3]);
      *(float4*)&val1[(size_t)n * D + d + 4] = make_float4(y[4], y[5], y[6], y[7]);
      uint4 pk;
      uint z0 = f2bf((y[0] - mean2) * rs2 * ln2g[d + 0] + ln2b[d + 0]);
      uint z1 = f2bf((y[1] - mean2) * rs2 * ln2g[d + 1] + ln2b[d + 1]);
      uint z2 = f2bf((y[2] - mean2) * rs2 * ln2g[d + 2] + ln2b[d + 2]);
      uint z3 = f2bf((y[3] - mean2) * rs2 * ln2g[d + 3] + ln2b[d + 3]);
      uint z4 = f2bf((y[4] - mean2) * rs2 * ln2g[d + 4] + ln2b[d + 4]);
      uint z5 = f2bf((y[5] - mean2) * rs2 * ln2g[d + 5] + ln2b[d + 5]);
      uint z6 = f2bf((y[6] - mean2) * rs2 * ln2g[d + 6] + ln2b[d + 6]);
      uint z7 = f2bf((y[7] - mean2) * rs2 * ln2g[d + 7] + ln2b[d + 7]);
      pk.x = z0 | (z1 << 16); pk.y = z2 | (z3 << 16);
      pk.z = z4 | (z5 << 16); pk.w = z6 | (z7 << 16);
      *(uint4*)&x2bf[(size_t)n * D + d] = pk;
    }
  }
}

} // anonymous namespace

extern "C" void kernel_launch(void* const* d_in, const int* in_sizes, int n_in,
                              void* d_out, int out_size, void* d_ws, size_t ws_size,
                              hipStream_t stream)
{
  (void)in_sizes; (void)n_in; (void)out_size; (void)ws_size;
  const int*   ids          = (const int*)d_in[0];
  const float* embed        = (const float*)d_in[1];
  const float* pos_emb      = (const float*)d_in[2];
  const float* ln_in_g      = (const float*)d_in[3];
  const float* ln_in_b      = (const float*)d_in[4];
  const float* anchor_state = (const float*)d_in[5];
  const float* anchor_val   = (const float*)d_in[6];
  const float* state_w      = (const float*)d_in[7];
  const float* state_b      = (const float*)d_in[8];
  const float* wq           = (const float*)d_in[9];
  const float* wk           = (const float*)d_in[10];
  const float* gate         = (const float*)d_in[11];
  const float* ln_g         = (const float*)d_in[12];
  const float* ln_b         = (const float*)d_in[13];
  const float* ffn_w1       = (const float*)d_in[14];
  const float* ffn_b1       = (const float*)d_in[15];
  const float* ffn_w2       = (const float*)d_in[16];
  const float* ffn_b2       = (const float*)d_in[17];
  const float* ln2_g        = (const float*)d_in[18];
  const float* ln2_b        = (const float*)d_in[19];
  float* out = (float*)d_out;

  float* wsf  = (float*)d_ws;
  float* val0 = wsf;  wsf += (size_t)N * D;      // layer input fp32 (residual)
  float* val1 = wsf;  wsf += (size_t)N * D;      // post-attn+LN1 (FFN2 residual)
  ushort* wsu   = (ushort*)wsf;
  ushort* val0bf = wsu;  wsu += (size_t)N * D;   // bf16 layer input
  ushort* x2bf   = wsu;  wsu += (size_t)N * D;   // bf16 LN2 out (FFN1 A)
  ushort* hbf    = wsu;  wsu += (size_t)N * HFF; // bf16 gelu out (FFN2 A)
  ushort* qkbf   = wsu;  wsu += (size_t)N * 256; // bf16 q|k per token
  ushort* wqkbf  = wsu;  wsu += (size_t)L * 256 * D;
  ushort* w1t    = wsu;  wsu += (size_t)L * HFF * D;
  ushort* w2t    = wsu;  wsu += (size_t)L * HFF * D;
  float* st0 = (float*)wsu;
  float* st1 = st0 + N;

  pack_wqk_bf<<<L * 512, 256, 0, stream>>>(wq, wk, wqkbf);
  transpose_bf<<<dim3(HFF / 32, D / 32, L), 256, 0, stream>>>(ffn_w1, w1t, D, HFF);
  transpose_bf<<<dim3(D / 32, HFF / 32, L), 256, 0, stream>>>(ffn_w2, w2t, HFF, D);
  embed_ln_kernel<<<N, 256, 0, stream>>>(ids, embed, pos_emb, ln_in_g, ln_in_b,
                                         anchor_val, anchor_state, state_w,
                                         state_b, val0, val0bf, st0);

  float* sin_  = st0;
  float* sout_ = st1;
  const int MT = (N + 63) / 64;   // 25 row tiles
  for (int l = 0; l < L; ++l){
    gemm_bf16<0><<<dim3(256 / 64, MT), 256, 0, stream>>>(
        val0bf, wqkbf + (size_t)l * 256 * D, nullptr, nullptr,
        nullptr, qkbf, N, D, 256);
    attn4_kernel<<<NB4, 256, 0, stream>>>(qkbf, val0, val0bf, sin_, val1, x2bf,
                                          sout_, gate + l, ln_g + l * D,
                                          ln_b + l * D, ln2_g + l * D,
                                          ln2_b + l * D);
    gemm_bf16<1><<<dim3(HFF / 64, MT), 256, 0, stream>>>(
        x2bf, w1t + (size_t)l * HFF * D, ffn_b1 + l * HFF, nullptr,
        nullptr, hbf, N, D, HFF);
    float* dst = (l == L - 1) ? out : val0;
    gemm_bf16<0><<<dim3(D / 64, MT), 256, 0, stream>>>(
        hbf, w2t + (size_t)l * HFF * D, ffn_b2 + l * D, val1,
        dst, val0bf, N, HFF, D);
    float* tmp = sin_; sin_ = sout_; sout_ = tmp;
  }
}

// Round 8
// 370.754 us; speedup vs baseline: 1.2775x; 1.2775x over previous
//
#include <hip/hip_runtime.h>
#include <hip/hip_bf16.h>

namespace {

constexpr int D    = 512;
constexpr int S    = 1536;
constexpr int N    = S + 1;      // 1537
constexpr int L    = 4;
constexpr int H    = 4;
constexpr int R    = 32;
constexpr int W    = 128;
constexpr int HFF  = 1024;
constexpr float EPS = 1e-5f;

// attention: 4 tokens/block, shared neighbor span
constexpr int TB   = 4;
constexpr int NB4  = (N + TB - 1) / TB;   // 385 blocks
constexpr int SP   = 133;    // c=0..131 window span (g = n0-W+c), c=132 anchor
constexpr int SPAD = 136;    // padded row stride

typedef __attribute__((ext_vector_type(8))) short short8;
typedef __attribute__((ext_vector_type(4))) float floatx4;

__device__ inline ushort f2bf(float x){
  __hip_bfloat16 h = __float2bfloat16(x);
  return *reinterpret_cast<ushort*>(&h);
}
__device__ inline float bf2f(uint u){
  union { uint u; float f; } c; c.u = u << 16; return c.f;
}

// ---------------- reductions ------------------------------------------------
__device__ inline float wave_sum(float v){
#pragma unroll
  for (int o = 32; o; o >>= 1) v += __shfl_xor(v, o, 64);
  return v;
}
__device__ inline float wave_max(float v){
#pragma unroll
  for (int o = 32; o; o >>= 1) v = fmaxf(v, __shfl_xor(v, o, 64));
  return v;
}
__device__ inline float block_sum(float v, float* scr){
  v = wave_sum(v);
  __syncthreads();
  if ((threadIdx.x & 63) == 0) scr[threadIdx.x >> 6] = v;
  __syncthreads();
  return scr[0] + scr[1] + scr[2] + scr[3];
}

// ---------------- pack wq/wk -> bf16 [l][c][d], c = q(0..127)|k(128..255) ----
__global__ __launch_bounds__(256) void pack_wqk_bf(const float* __restrict__ wq,
                                                   const float* __restrict__ wk,
                                                   ushort* __restrict__ out){
  int i = blockIdx.x * 256 + threadIdx.x;   // L*256*512
  int d = i & 511;
  int c = (i >> 9) & 255;
  int l = i >> 17;
  int cc = c & 127;
  int h = cc >> 5, r = cc & 31;
  const float* src = (c < 128) ? wq : wk;
  out[i] = f2bf(src[((l * H + h) * D + d) * R + r]);
}

// ---------------- fp32 [rows][cols] -> bf16 [cols][rows], per-layer grid.z ---
__global__ __launch_bounds__(256) void transpose_bf(const float* __restrict__ src,
                                                    ushort* __restrict__ dst,
                                                    int rows, int cols){
  __shared__ float tile[32][33];
  const float* s = src + (size_t)blockIdx.z * rows * cols;
  ushort* d = dst + (size_t)blockIdx.z * rows * cols;
  int c0 = blockIdx.x * 32, r0 = blockIdx.y * 32;
  int tx = threadIdx.x & 31, ty = threadIdx.x >> 5;
  for (int rr = ty; rr < 32; rr += 8)
    tile[rr][tx] = s[(size_t)(r0 + rr) * cols + c0 + tx];
  __syncthreads();
  for (int rr = ty; rr < 32; rr += 8)
    d[(size_t)(c0 + rr) * rows + r0 + tx] = f2bf(tile[tx][rr]);
}

// ---------------- embedding + input LN + tok_state --------------------------
__global__ __launch_bounds__(256) void embed_ln_kernel(
    const int* __restrict__ ids, const float* __restrict__ embed,
    const float* __restrict__ pos, const float* __restrict__ g,
    const float* __restrict__ b, const float* __restrict__ anchor_val,
    const float* __restrict__ anchor_state, const float* __restrict__ state_w,
    const float* __restrict__ state_b, float* __restrict__ val,
    ushort* __restrict__ valbf, float* __restrict__ state)
{
  __shared__ float scr[4];
  int n = blockIdx.x, t = threadIdx.x;
  if (n == 0){
    float a0 = anchor_val[t], a1 = anchor_val[t + 256];
    val[t] = a0; val[t + 256] = a1;
    valbf[t] = f2bf(a0); valbf[t + 256] = f2bf(a1);
    if (t == 0) state[0] = anchor_state[0];
    return;
  }
  int tp = n - 1;
  int id = ids[tp];
  float x0 = embed[(size_t)id * D + t]       + pos[tp * D + t];
  float x1 = embed[(size_t)id * D + t + 256] + pos[tp * D + t + 256];
  float mean = block_sum(x0 + x1, scr) * (1.f / D);
  float var  = block_sum(x0 * x0 + x1 * x1, scr) * (1.f / D) - mean * mean;
  float rs   = rsqrtf(var + EPS);
  float y0 = (x0 - mean) * rs * g[t]       + b[t];
  float y1 = (x1 - mean) * rs * g[t + 256] + b[t + 256];
  val[n * D + t]       = y0;
  val[n * D + t + 256] = y1;
  valbf[n * D + t]       = f2bf(y0);
  valbf[n * D + t + 256] = f2bf(y1);
  float ts = block_sum(y0 * state_w[t] + y1 * state_w[t + 256], scr);
  if (t == 0) state[n] = ts + state_b[0];
}

// ---------------- bf16 MFMA GEMM: C = act(A * Bt^T + bias) (+resid) ---------
// A: [M][Kd] bf16; Bt: [Nc][Kd] bf16. 32x32 tile, BK=64, 256 threads = 4
// waves; each wave one 16x16 quadrant (wr=w&1 row half, wc=w>>1 col half).
// Small tile -> big grid (QK 392 / FFN1 1568 / FFN2 784 blocks) so 3-6
// blocks/CU give cross-block latency hiding (m114). 8.5 KB LDS, low VGPR.
template<int ACT>
__global__ __launch_bounds__(256) void gemm_bf16(
    const ushort* __restrict__ A, const ushort* __restrict__ Bt,
    const float* __restrict__ bias, const float* __restrict__ resid,
    float* __restrict__ C, ushort* __restrict__ Cbf,
    int M, int Kd, int Nc)
{
  constexpr int SLAB = 272;     // 32 rows * 8 ushorts + 16 pad
  __shared__ ushort As[8 * SLAB];
  __shared__ ushort Bs[8 * SLAB];
  int row0 = blockIdx.y * 32;
  int col0 = blockIdx.x * 32;
  int t = threadIdx.x;
  int lane = t & 63, w = t >> 6;
  int wr = w & 1, wc = w >> 1;
  int q = lane >> 4, lm = lane & 15;

  // staging: thread t handles A slot t and B slot t; slot: row=t>>3 (0..31),
  // k-block=t&7 (8 ushorts each) -> one 16B load + one 16B LDS write per mat.
  int srow = t >> 3, skb = t & 7;
  int arow = min(row0 + srow, M - 1);   // clamp: OOB rows never written back
  const ushort* ag = A  + (size_t)arow * Kd + skb * 8;
  const ushort* bg = Bt + (size_t)(col0 + srow) * Kd + skb * 8;
  ushort* as = &As[skb * SLAB + srow * 8];
  ushort* bs = &Bs[skb * SLAB + srow * 8];

  // fragment bases: lane(q,lm) reads k-block (kk*4+q), row/col 16*half+lm
  const ushort* ar = &As[(wr * 16 + lm) * 8];
  const ushort* br = &Bs[(wc * 16 + lm) * 8];

  floatx4 acc = {0.f, 0.f, 0.f, 0.f};

  for (int k0 = 0; k0 < Kd; k0 += 64){
    uint4 av = *(const uint4*)(ag + k0);
    uint4 bv = *(const uint4*)(bg + k0);
    *(uint4*)as = av;
    *(uint4*)bs = bv;
    __syncthreads();
#pragma unroll
    for (int kk = 0; kk < 2; ++kk){
      short8 a = *(const short8*)(ar + (kk * 4 + q) * SLAB);
      short8 b = *(const short8*)(br + (kk * 4 + q) * SLAB);
      acc = __builtin_amdgcn_mfma_f32_16x16x32_bf16(a, b, acc, 0, 0, 0);
    }
    __syncthreads();
  }

  // epilogue: C/D layout col = lane&15, row = (lane>>4)*4 + reg  [m89]
  int col = col0 + wc * 16 + lm;
#pragma unroll
  for (int r = 0; r < 4; ++r){
    int row = row0 + wr * 16 + q * 4 + r;
    if (row >= M) continue;
    float v = acc[r] + (bias ? bias[col] : 0.f);
    if (ACT == 1) v = 0.5f * v * (1.f + erff(v * 0.70710678118654752f));
    if (resid) v += resid[(size_t)row * Nc + col];
    size_t o = (size_t)row * Nc + col;
    if (C)   C[o] = v;
    if (Cbf) Cbf[o] = f2bf(v);
  }
}

// ---------------- attention, 4 tokens per block ------------------------------
// qkbf: [N][256] bf16 (q 0..127 = h*32+r, k 128..255).
// Span col c: 0..131 -> global g = n0 - W + c (clamped); c=132 -> anchor (0).
// Token i (n = n0+i) window = c in [i, i+128]; anchor valid iff n > W.
__global__ __launch_bounds__(256) void attn4_kernel(
    const ushort* __restrict__ qkbf, const float* __restrict__ val0,
    const ushort* __restrict__ val0bf, const float* __restrict__ state_in,
    float* __restrict__ val1, ushort* __restrict__ x2bf,
    float* __restrict__ state_out,
    const float* __restrict__ gate_p, const float* __restrict__ lng,
    const float* __restrict__ lnb, const float* __restrict__ ln2g,
    const float* __restrict__ ln2b)
{
  __shared__ float kg[64 * SPAD];   // [ch_local][c], reused as xbuf[4][520] later
  __shared__ float qsh[TB * 128];
  __shared__ float ssh[16 * SPAD];  // [tok*4+h][c]
  __shared__ float ash[TB * SPAD];  // a then e, row per token
  const int n0 = blockIdx.x * TB;
  const int t = threadIdx.x;
  const int w = t >> 6, l = t & 63;   // wave = token index
  const float gate = gate_p[0];
  const float scale = 0.17677669529663687f;  // 1/sqrt(32)

  // ---- stage q (4 tokens x 128 ch)
#pragma unroll
  for (int i = t; i < TB * 128; i += 256){
    int it = i >> 7, ch = i & 127;
    int gr = min(n0 + it, N - 1);
    qsh[i] = bf2f((uint)qkbf[(size_t)gr * 256 + ch]);
  }

  // ---- scores, two halves of 64 channels
  for (int half = 0; half < 2; ++half){
    for (int i = t; i < SP * 16; i += 256){
      int c = i >> 4, c4 = i & 15;
      int g = (c == 132) ? 0 : min(max(n0 - W + c, 0), N - 1);
      uint2 v = *(const uint2*)&qkbf[(size_t)g * 256 + 128 + half * 64 + c4 * 4];
      int ch = c4 * 4;
      kg[(ch + 0) * SPAD + c] = bf2f(v.x & 0xffffu);
      kg[(ch + 1) * SPAD + c] = bf2f(v.x >> 16);
      kg[(ch + 2) * SPAD + c] = bf2f(v.y & 0xffffu);
      kg[(ch + 3) * SPAD + c] = bf2f(v.y >> 16);
    }
    __syncthreads();
    for (int tk = t; tk < TB * 2 * SP; tk += 256){
      int c = tk % SP;
      int th = tk / SP;            // 0..7
      int tok = th & 3, hh = th >> 2;
      int h = half * 2 + hh;
      const float* qs = &qsh[tok * 128 + h * 32];
      const float* ks = &kg[hh * 32 * SPAD + c];
      float acc = 0.f;
#pragma unroll
      for (int r = 0; r < 32; ++r) acc += qs[r] * ks[r * SPAD];
      ssh[(tok * 4 + h) * SPAD + c] = acc * scale;
    }
    __syncthreads();
  }

  // ---- per-(tok,c) head softmax -> a
  for (int i = t; i < TB * SP; i += 256){
    int tok = i / SP, c = i - tok * SP;
    const float* sr = &ssh[tok * 4 * SPAD + c];
    float s0 = sr[0], s1 = sr[SPAD], s2 = sr[2 * SPAD], s3 = sr[3 * SPAD];
    float a0 = fabsf(s0), a1 = fabsf(s1), a2 = fabsf(s2), a3 = fabsf(s3);
    float m = fmaxf(fmaxf(a0, a1), fmaxf(a2, a3));
    float w0 = expf(a0 - m), w1 = expf(a1 - m), w2 = expf(a2 - m), w3 = expf(a3 - m);
    ash[tok * SPAD + c] = (s0 * w0 + s1 * w1 + s2 * w2 + s3 * w3) / (w0 + w1 + w2 + w3);
  }
  __syncthreads();

  // ---- per-token signed softmax over span (wave w <-> token w), e in place
  {
    const int n = n0 + w;
    float* arow = &ash[w * SPAD];
    float a0 = arow[l];
    float a1 = arow[64 + l];
    float a2 = (l < 5) ? arow[128 + l] : 0.f;
    bool ok0 = (l >= w) && (n0 - W + l >= 0);
    bool ok1 = (n0 - W + 64 + l >= 0);
    bool ok2;
    if (l < 4)       ok2 = (l <= w);          // window col 128+l, g = n0+l >= 0
    else if (l == 4) ok2 = (n > W);           // anchor (c=132)
    else             ok2 = false;
    float cand = -3.4e38f;
    if (ok0) cand = fabsf(a0);
    if (ok1) cand = fmaxf(cand, fabsf(a1));
    if (ok2) cand = fmaxf(cand, fabsf(a2));
    float m = wave_max(cand);
    float e0 = ok0 ? expf(fabsf(a0) - m) : 0.f;
    float e1 = ok1 ? expf(fabsf(a1) - m) : 0.f;
    float e2 = ok2 ? expf(fabsf(a2) - m) : 0.f;
    float inv = 1.f / wave_sum(e0 + e1 + e2);
    int g0 = min(max(n0 - W + l, 0), N - 1);
    int g1 = min(max(n0 - W + 64 + l, 0), N - 1);
    int g2 = (l < 4) ? min(n0 + l, N - 1) : 0;
    float sg0 = (a0 > 0.f) ? 1.f : ((a0 < 0.f) ? -1.f : 0.f);
    float sg1 = (a1 > 0.f) ? 1.f : ((a1 < 0.f) ? -1.f : 0.f);
    float sg2 = (a2 > 0.f) ? 1.f : ((a2 < 0.f) ? -1.f : 0.f);
    float t0 = sg0 * e0 * inv * state_in[g0];
    float t1 = sg1 * e1 * inv * state_in[g1];
    float t2 = (l < 5) ? sg2 * e2 * inv * state_in[g2] : 0.f;
    arow[l] = t0;
    arow[64 + l] = t1;
    if (l < 5) arow[128 + l] = t2;
    float ds = wave_sum(t0 + t1 + t2);
    if (l == 0 && n < N) state_out[n] = state_in[n] + gate * ds;
  }
  __syncthreads();

  // ---- d_val: stream span rows once (bf16), 4 accumulators per thread
  float acc[TB][2];
#pragma unroll
  for (int k = 0; k < TB; ++k){ acc[k][0] = 0.f; acc[k][1] = 0.f; }
  {
    const int d0 = 2 * t;
    for (int c = 0; c < SP; ++c){
      int g = (c == 132) ? 0 : min(max(n0 - W + c, 0), N - 1);
      uint v = *(const uint*)&val0bf[(size_t)g * D + d0];
      float vx = bf2f(v & 0xffffu), vy = bf2f(v >> 16);
#pragma unroll
      for (int k = 0; k < TB; ++k){
        float e = ash[k * SPAD + c];
        acc[k][0] += e * vx;
        acc[k][1] += e * vy;
      }
    }
  }
  // residual into xbuf (reuse kg; kg dead after scores)
  float* xbuf = kg;    // [4][520]
  {
    const int d0 = 2 * t;
#pragma unroll
    for (int k = 0; k < TB; ++k){
      int nc = min(n0 + k, N - 1);
      float2 vv = *(const float2*)&val0[(size_t)nc * D + d0];
      xbuf[k * 520 + d0]     = vv.x + gate * acc[k][0];
      xbuf[k * 520 + d0 + 1] = vv.y + gate * acc[k][1];
    }
  }
  __syncthreads();

  // ---- LN1 -> val1, LN2 -> x2bf (wave per token, 8 dims per lane)
  {
    const int n = n0 + w;
    const int d = l * 8;
    const float* xr = &xbuf[w * 520 + d];
    float x[8];
#pragma unroll
    for (int j = 0; j < 8; ++j) x[j] = xr[j];
    float s1 = 0.f, s2 = 0.f;
#pragma unroll
    for (int j = 0; j < 8; ++j){ s1 += x[j]; s2 += x[j] * x[j]; }
    s1 = wave_sum(s1); s2 = wave_sum(s2);
    float mean = s1 * (1.f / D);
    float var  = s2 * (1.f / D) - mean * mean;
    float rs   = rsqrtf(var + EPS);
    float y[8];
    float u1 = 0.f, u2 = 0.f;
#pragma unroll
    for (int j = 0; j < 8; ++j){
      float yv = (x[j] - mean) * rs * lng[d + j] + lnb[d + j];
      y[j] = yv; u1 += yv; u2 += yv * yv;
    }
    u1 = wave_sum(u1); u2 = wave_sum(u2);
    float mean2 = u1 * (1.f / D);
    float var2  = u2 * (1.f / D) - mean2 * mean2;
    float rs2   = rsqrtf(var2 + EPS);
    if (n < N){
      *(float4*)&val1[(size_t)n * D + d]     = make_float4(y[0], y[1], y[2], y[3]);
      *(float4*)&val1[(size_t)n * D + d + 4] = make_float4(y[4], y[5], y[6], y[7]);
      uint4 pk;
      uint z0 = f2bf((y[0] - mean2) * rs2 * ln2g[d + 0] + ln2b[d + 0]);
      uint z1 = f2bf((y[1] - mean2) * rs2 * ln2g[d + 1] + ln2b[d + 1]);
      uint z2 = f2bf((y[2] - mean2) * rs2 * ln2g[d + 2] + ln2b[d + 2]);
      uint z3 = f2bf((y[3] - mean2) * rs2 * ln2g[d + 3] + ln2b[d + 3]);
      uint z4 = f2bf((y[4] - mean2) * rs2 * ln2g[d + 4] + ln2b[d + 4]);
      uint z5 = f2bf((y[5] - mean2) * rs2 * ln2g[d + 5] + ln2b[d + 5]);
      uint z6 = f2bf((y[6] - mean2) * rs2 * ln2g[d + 6] + ln2b[d + 6]);
      uint z7 = f2bf((y[7] - mean2) * rs2 * ln2g[d + 7] + ln2b[d + 7]);
      pk.x = z0 | (z1 << 16); pk.y = z2 | (z3 << 16);
      pk.z = z4 | (z5 << 16); pk.w = z6 | (z7 << 16);
      *(uint4*)&x2bf[(size_t)n * D + d] = pk;
    }
  }
}

} // anonymous namespace

extern "C" void kernel_launch(void* const* d_in, const int* in_sizes, int n_in,
                              void* d_out, int out_size, void* d_ws, size_t ws_size,
                              hipStream_t stream)
{
  (void)in_sizes; (void)n_in; (void)out_size; (void)ws_size;
  const int*   ids          = (const int*)d_in[0];
  const float* embed        = (const float*)d_in[1];
  const float* pos_emb      = (const float*)d_in[2];
  const float* ln_in_g      = (const float*)d_in[3];
  const float* ln_in_b      = (const float*)d_in[4];
  const float* anchor_state = (const float*)d_in[5];
  const float* anchor_val   = (const float*)d_in[6];
  const float* state_w      = (const float*)d_in[7];
  const float* state_b      = (const float*)d_in[8];
  const float* wq           = (const float*)d_in[9];
  const float* wk           = (const float*)d_in[10];
  const float* gate         = (const float*)d_in[11];
  const float* ln_g         = (const float*)d_in[12];
  const float* ln_b         = (const float*)d_in[13];
  const float* ffn_w1       = (const float*)d_in[14];
  const float* ffn_b1       = (const float*)d_in[15];
  const float* ffn_w2       = (const float*)d_in[16];
  const float* ffn_b2       = (const float*)d_in[17];
  const float* ln2_g        = (const float*)d_in[18];
  const float* ln2_b        = (const float*)d_in[19];
  float* out = (float*)d_out;

  float* wsf  = (float*)d_ws;
  float* val0 = wsf;  wsf += (size_t)N * D;      // layer input fp32 (residual)
  float* val1 = wsf;  wsf += (size_t)N * D;      // post-attn+LN1 (FFN2 residual)
  ushort* wsu   = (ushort*)wsf;
  ushort* val0bf = wsu;  wsu += (size_t)N * D;   // bf16 layer input
  ushort* x2bf   = wsu;  wsu += (size_t)N * D;   // bf16 LN2 out (FFN1 A)
  ushort* hbf    = wsu;  wsu += (size_t)N * HFF; // bf16 gelu out (FFN2 A)
  ushort* qkbf   = wsu;  wsu += (size_t)N * 256; // bf16 q|k per token
  ushort* wqkbf  = wsu;  wsu += (size_t)L * 256 * D;
  ushort* w1t    = wsu;  wsu += (size_t)L * HFF * D;
  ushort* w2t    = wsu;  wsu += (size_t)L * HFF * D;
  float* st0 = (float*)wsu;
  float* st1 = st0 + N;

  pack_wqk_bf<<<L * 512, 256, 0, stream>>>(wq, wk, wqkbf);
  transpose_bf<<<dim3(HFF / 32, D / 32, L), 256, 0, stream>>>(ffn_w1, w1t, D, HFF);
  transpose_bf<<<dim3(D / 32, HFF / 32, L), 256, 0, stream>>>(ffn_w2, w2t, HFF, D);
  embed_ln_kernel<<<N, 256, 0, stream>>>(ids, embed, pos_emb, ln_in_g, ln_in_b,
                                         anchor_val, anchor_state, state_w,
                                         state_b, val0, val0bf, st0);

  float* sin_  = st0;
  float* sout_ = st1;
  const int MT32 = (N + 31) / 32;   // 49 row tiles
  for (int l = 0; l < L; ++l){
    gemm_bf16<0><<<dim3(256 / 32, MT32), 256, 0, stream>>>(
        val0bf, wqkbf + (size_t)l * 256 * D, nullptr, nullptr,
        nullptr, qkbf, N, D, 256);
    attn4_kernel<<<NB4, 256, 0, stream>>>(qkbf, val0, val0bf, sin_, val1, x2bf,
                                          sout_, gate + l, ln_g + l * D,
                                          ln_b + l * D, ln2_g + l * D,
                                          ln2_b + l * D);
    gemm_bf16<1><<<dim3(HFF / 32, MT32), 256, 0, stream>>>(
        x2bf, w1t + (size_t)l * HFF * D, ffn_b1 + l * HFF, nullptr,
        nullptr, hbf, N, D, HFF);
    float* dst = (l == L - 1) ? out : val0;
    gemm_bf16<0><<<dim3(D / 32, MT32), 256, 0, stream>>>(
        hbf, w2t + (size_t)l * HFF * D, ffn_b2 + l * D, val1,
        dst, val0bf, N, HFF, D);
    float* tmp = sin_; sin_ = sout_; sout_ = tmp;
  }
}